// Round 7
// baseline (1068.322 us; speedup 1.0000x reference)
//
#include <hip/hip_runtime.h>
#include <hip/hip_fp16.h>
#include <hip/hip_cooperative_groups.h>
#include <math.h>

#define D 128
#define PADH 136   // LDS row stride in halves (272 B): 2-way bank alias only (free)
#define NB 1024    // cooperative grid: 4 blocks/CU x 256 CUs
#define NT 256

namespace cg = cooperative_groups;

typedef __attribute__((ext_vector_type(8))) _Float16 half8;
typedef __attribute__((ext_vector_type(4))) _Float16 half4v;
typedef __attribute__((ext_vector_type(4))) float f32x4;

// ---------------- dual-row gather (R4, proven) ----------------
// Lanes 0-31 process row r0, lanes 32-63 row r1; each lane holds 4 halves (8B).
// One gather instruction fetches BOTH rows' 256B lines.

__device__ __forceinline__ float4 gather2(const __half* __restrict__ g,
                                          const int* __restrict__ rowptr,
                                          const int* __restrict__ col,
                                          int r0, int r1, int lane) {
    int half = lane >> 5;
    int l32  = lane & 31;
    int hb   = half << 5;
    int row  = half ? r1 : r0;
    int s = rowptr[row], e = rowptr[row + 1];

    half4v hs = ((const half4v*)(g + (size_t)row * D))[l32];
    float4 A = make_float4((float)hs[0], (float)hs[1], (float)hs[2], (float)hs[3]);
    float4 B = make_float4(0.f, 0.f, 0.f, 0.f);

    for (int base = s; base < e; base += 32) {
        int idx = base + l32;
        int myc = (idx < e) ? col[idx] : 0;
        int nb  = min(32, e - base);
        int j = 0;
        for (; j + 8 <= nb; j += 8) {
            int c0 = __shfl(myc, hb + j + 0), c1 = __shfl(myc, hb + j + 1);
            int c2 = __shfl(myc, hb + j + 2), c3 = __shfl(myc, hb + j + 3);
            int c4 = __shfl(myc, hb + j + 4), c5 = __shfl(myc, hb + j + 5);
            int c6 = __shfl(myc, hb + j + 6), c7 = __shfl(myc, hb + j + 7);
            half4v v0 = ((const half4v*)(g + (size_t)c0 * D))[l32];
            half4v v1 = ((const half4v*)(g + (size_t)c1 * D))[l32];
            half4v v2 = ((const half4v*)(g + (size_t)c2 * D))[l32];
            half4v v3 = ((const half4v*)(g + (size_t)c3 * D))[l32];
            half4v v4 = ((const half4v*)(g + (size_t)c4 * D))[l32];
            half4v v5 = ((const half4v*)(g + (size_t)c5 * D))[l32];
            half4v v6 = ((const half4v*)(g + (size_t)c6 * D))[l32];
            half4v v7 = ((const half4v*)(g + (size_t)c7 * D))[l32];
            A.x += (float)v0[0]; A.y += (float)v0[1]; A.z += (float)v0[2]; A.w += (float)v0[3];
            B.x += (float)v1[0]; B.y += (float)v1[1]; B.z += (float)v1[2]; B.w += (float)v1[3];
            A.x += (float)v2[0]; A.y += (float)v2[1]; A.z += (float)v2[2]; A.w += (float)v2[3];
            B.x += (float)v3[0]; B.y += (float)v3[1]; B.z += (float)v3[2]; B.w += (float)v3[3];
            A.x += (float)v4[0]; A.y += (float)v4[1]; A.z += (float)v4[2]; A.w += (float)v4[3];
            B.x += (float)v5[0]; B.y += (float)v5[1]; B.z += (float)v5[2]; B.w += (float)v5[3];
            A.x += (float)v6[0]; A.y += (float)v6[1]; A.z += (float)v6[2]; A.w += (float)v6[3];
            B.x += (float)v7[0]; B.y += (float)v7[1]; B.z += (float)v7[2]; B.w += (float)v7[3];
        }
        for (; j + 4 <= nb; j += 4) {
            int c0 = __shfl(myc, hb + j + 0), c1 = __shfl(myc, hb + j + 1);
            int c2 = __shfl(myc, hb + j + 2), c3 = __shfl(myc, hb + j + 3);
            half4v v0 = ((const half4v*)(g + (size_t)c0 * D))[l32];
            half4v v1 = ((const half4v*)(g + (size_t)c1 * D))[l32];
            half4v v2 = ((const half4v*)(g + (size_t)c2 * D))[l32];
            half4v v3 = ((const half4v*)(g + (size_t)c3 * D))[l32];
            A.x += (float)v0[0]; A.y += (float)v0[1]; A.z += (float)v0[2]; A.w += (float)v0[3];
            B.x += (float)v1[0]; B.y += (float)v1[1]; B.z += (float)v1[2]; B.w += (float)v1[3];
            A.x += (float)v2[0]; A.y += (float)v2[1]; A.z += (float)v2[2]; A.w += (float)v2[3];
            B.x += (float)v3[0]; B.y += (float)v3[1]; B.z += (float)v3[2]; B.w += (float)v3[3];
        }
        for (; j < nb; ++j) {
            int c = __shfl(myc, hb + j);
            half4v v = ((const half4v*)(g + (size_t)c * D))[l32];
            A.x += (float)v[0]; A.y += (float)v[1]; A.z += (float)v[2]; A.w += (float)v[3];
        }
    }
    A.x += B.x; A.y += B.y; A.z += B.z; A.w += B.w;
    return A;
}

// ==================================================================
// MEGA KERNEL: entire 3-layer GCN in ONE cooperative dispatch.
// Phases separated by grid.sync(); NO early returns anywhere.
// ==================================================================

__global__ __launch_bounds__(NT, 4) void mega_kernel(
    const float* __restrict__ X, const int* __restrict__ src, const int* __restrict__ dst,
    const float* __restrict__ W1, const float* __restrict__ b1,
    const float* __restrict__ W2, const float* __restrict__ b2,
    const float* __restrict__ W3, const float* __restrict__ b3,
    float* __restrict__ out,
    __half* __restrict__ ys, __half* __restrict__ hs,
    int* __restrict__ cnt, int* __restrict__ rowptr, float* __restrict__ dinv,
    int* __restrict__ rank, int* __restrict__ col, int* __restrict__ partials,
    __half* __restrict__ WhT, int N, int E)
{
    cg::grid_group grid = cg::this_grid();
    const int tid  = threadIdx.x;
    const int bid  = blockIdx.x;
    const int nb   = gridDim.x;
    const int gid  = bid * NT + tid;
    const int gsz  = nb * NT;
    const int lane = tid & 63;
    const int wid  = tid >> 6;

    __shared__ __half lds_h[16 * PADH];
    __shared__ int sred[4];

    // ---- P0: WhT[l][n][k] = (half)Wl[k][n]; cnt = 0 ----
    for (int i = gid; i < 3 * D * D; i += gsz) {
        int l = i >> 14, j = i & 16383, n = j >> 7, k = j & 127;
        const float* W = (l == 0) ? W1 : (l == 1) ? W2 : W3;
        WhT[i] = __float2half(W[(size_t)k * D + n]);
    }
    for (int i = gid; i < N; i += gsz) cnt[i] = 0;
    grid.sync();

    // ---- P1: count + rank (arrival order per dst bucket) ----
    const int NO = (E + 7) / 8;
    for (int c = gid; c < NO; c += gsz) {
        int e0 = c * 8;
        if (e0 + 7 < E) {
            int4 da = *(const int4*)(dst + e0);
            int4 db = *(const int4*)(dst + e0 + 4);
            int4 ra, rb;
            ra.x = atomicAdd(&cnt[da.x], 1);
            ra.y = atomicAdd(&cnt[da.y], 1);
            ra.z = atomicAdd(&cnt[da.z], 1);
            ra.w = atomicAdd(&cnt[da.w], 1);
            rb.x = atomicAdd(&cnt[db.x], 1);
            rb.y = atomicAdd(&cnt[db.y], 1);
            rb.z = atomicAdd(&cnt[db.z], 1);
            rb.w = atomicAdd(&cnt[db.w], 1);
            *(int4*)(rank + e0)     = ra;
            *(int4*)(rank + e0 + 4) = rb;
        } else {
            for (int e = e0; e < E; ++e) rank[e] = atomicAdd(&cnt[dst[e]], 1);
        }
    }
    grid.sync();

    // ---- P2a: per-thread 4-row sums + dinv; per-block partial sum ----
    int4 myv = make_int4(0, 0, 0, 0);
    int mysum = 0;
    const int t4 = gid * 4;
    if (t4 < N) {
        if (t4 + 3 < N) myv = *(const int4*)(cnt + t4);
        else {
            myv.x = cnt[t4];
            if (t4 + 1 < N) myv.y = cnt[t4 + 1];
            if (t4 + 2 < N) myv.z = cnt[t4 + 2];
        }
        mysum = myv.x + myv.y + myv.z + myv.w;
        dinv[t4] = rsqrtf((float)myv.x + 1.0f);
        if (t4 + 1 < N) dinv[t4 + 1] = rsqrtf((float)myv.y + 1.0f);
        if (t4 + 2 < N) dinv[t4 + 2] = rsqrtf((float)myv.z + 1.0f);
        if (t4 + 3 < N) dinv[t4 + 3] = rsqrtf((float)myv.w + 1.0f);
    }
    {
        int rs = mysum;
        #pragma unroll
        for (int off = 32; off > 0; off >>= 1) rs += __shfl_down(rs, off, 64);
        if (lane == 0) sred[wid] = rs;
        __syncthreads();
        if (tid == 0) partials[bid] = sred[0] + sred[1] + sred[2] + sred[3];
    }
    grid.sync();

    // ---- P2b: block-scan + global base -> rowptr ----
    {
        int sc = mysum;
        #pragma unroll
        for (int off = 1; off < 64; off <<= 1) {
            int t = __shfl_up(sc, off, 64);
            if (lane >= off) sc += t;
        }
        __syncthreads();   // sred reuse guard
        if (lane == 63) sred[wid] = sc;
        __syncthreads();
        int waveoff = 0;
        #pragma unroll
        for (int w = 0; w < 4; ++w) if (w < wid) waveoff += sred[w];
        if (t4 < N) {
            int base = 0;
            for (int b = 0; b < bid; ++b) base += partials[b];   // <=48 useful blocks
            int run = base + waveoff + (sc - mysum);
            rowptr[t4] = run;                 run += myv.x;
            if (t4 + 1 < N) rowptr[t4 + 1] = run; run += myv.y;
            if (t4 + 2 < N) rowptr[t4 + 2] = run; run += myv.z;
            if (t4 + 3 < N) rowptr[t4 + 3] = run;
        }
        if (gid == 0) rowptr[N] = E;          // total degree == E
    }
    grid.sync();

    // ---- P3: fill (blocks [0,FB)) || gemm1 (blocks [FB,nb)) ----
    const int FB = nb / 2;
    if (bid < FB) {
        const int fsz = FB * NT;
        for (int c = bid * NT + tid; c < NO; c += fsz) {
            int e0 = c * 8;
            if (e0 + 7 < E) {
                int4 da = *(const int4*)(dst + e0);
                int4 db = *(const int4*)(dst + e0 + 4);
                int4 ra = *(const int4*)(rank + e0);
                int4 rb = *(const int4*)(rank + e0 + 4);
                int4 sa = *(const int4*)(src + e0);
                int4 sb = *(const int4*)(src + e0 + 4);
                col[rowptr[da.x] + ra.x] = sa.x;
                col[rowptr[da.y] + ra.y] = sa.y;
                col[rowptr[da.z] + ra.z] = sa.z;
                col[rowptr[da.w] + ra.w] = sa.w;
                col[rowptr[db.x] + rb.x] = sb.x;
                col[rowptr[db.y] + rb.y] = sb.y;
                col[rowptr[db.z] + rb.z] = sb.z;
                col[rowptr[db.w] + rb.w] = sb.w;
            } else {
                for (int e = e0; e < E; ++e) col[rowptr[dst[e]] + rank[e]] = src[e];
            }
        }
    } else {
        const int ntile = (N + 63) / 64;
        const int quad = lane >> 4, l16 = lane & 15;
        for (int t = bid - FB; t < ntile; t += nb - FB) {
            int m0 = t * 64 + wid * 16;
            if (m0 < N) {
                f32x4 acc[8];
                #pragma unroll
                for (int q = 0; q < 8; ++q) acc[q] = (f32x4)0.0f;
                const float* xrow = X + (size_t)(m0 + l16) * D;
                #pragma unroll
                for (int ks = 0; ks < 4; ++ks) {
                    int k0 = ks * 32 + quad * 8;
                    float4 x0 = *(const float4*)(xrow + k0);
                    float4 x1 = *(const float4*)(xrow + k0 + 4);
                    half8 a;
                    a[0] = (_Float16)x0.x; a[1] = (_Float16)x0.y;
                    a[2] = (_Float16)x0.z; a[3] = (_Float16)x0.w;
                    a[4] = (_Float16)x1.x; a[5] = (_Float16)x1.y;
                    a[6] = (_Float16)x1.z; a[7] = (_Float16)x1.w;
                    #pragma unroll
                    for (int q = 0; q < 8; ++q) {
                        half8 b = *(const half8*)(WhT + (size_t)(q * 16 + l16) * D + k0);
                        acc[q] = __builtin_amdgcn_mfma_f32_16x16x32_f16(a, b, acc[q], 0, 0, 0);
                    }
                }
                float4 dv = *(const float4*)(dinv + m0 + quad * 4);
                float dvs[4] = {dv.x, dv.y, dv.z, dv.w};
                #pragma unroll
                for (int q = 0; q < 8; ++q) {
                    #pragma unroll
                    for (int r = 0; r < 4; ++r) {
                        int grow = m0 + quad * 4 + r;
                        ys[(size_t)grow * D + q * 16 + l16] = __float2half(acc[q][r] * dvs[r]);
                    }
                }
            }
        }
    }
    grid.sync();

    // ---- P4/P5: fused aggregate+GEMM x2 (R4 body, grid-stride tiles) ----
    #pragma unroll 1
    for (int layer = 0; layer < 2; ++layer) {
        const __half* gin   = (layer == 0) ? ys : hs;
        __half*       gout  = (layer == 0) ? hs : ys;
        const float*  bias  = (layer == 0) ? b1 : b2;
        const __half* WhTl  = WhT + (layer == 0 ? 16384 : 32768);

        const int hf  = lane >> 5;
        const int l32 = lane & 31;
        const int quad = lane >> 4, l16 = lane & 15;
        const int t0 = wid * 2;
        float4 bb = ((const float4*)bias)[l32];
        const int ntile = (N + 15) / 16;

        for (int tile = bid; tile < ntile; tile += nb) {
            int rbase = tile * 16;
            #pragma unroll
            for (int t = 0; t < 2; ++t) {
                int lr0 = wid * 4 + t * 2;
                int row0 = rbase + lr0;
                int c0 = min(row0, N - 1);
                int c1 = min(row0 + 1, N - 1);
                float4 a = gather2(gin, rowptr, col, c0, c1, lane);
                int myrow = hf ? c1 : c0;
                float dv = dinv[myrow];
                half4v hv;
                hv[0] = (_Float16)fmaxf(bb.x + dv * a.x, 0.f);
                hv[1] = (_Float16)fmaxf(bb.y + dv * a.y, 0.f);
                hv[2] = (_Float16)fmaxf(bb.z + dv * a.z, 0.f);
                hv[3] = (_Float16)fmaxf(bb.w + dv * a.w, 0.f);
                ((half4v*)(lds_h + (size_t)(lr0 + hf) * PADH))[l32] = hv;
            }
            __syncthreads();

            f32x4 acc0 = (f32x4)0.0f, acc1 = (f32x4)0.0f;
            const __half* arow = lds_h + (size_t)l16 * PADH;
            #pragma unroll
            for (int ks = 0; ks < 4; ++ks) {
                int k0 = ks * 32 + quad * 8;
                half8 a  = *(const half8*)(arow + k0);
                half8 b0 = *(const half8*)(WhTl + (size_t)((t0 + 0) * 16 + l16) * D + k0);
                half8 b1v = *(const half8*)(WhTl + (size_t)((t0 + 1) * 16 + l16) * D + k0);
                acc0 = __builtin_amdgcn_mfma_f32_16x16x32_f16(a, b0, acc0, 0, 0, 0);
                acc1 = __builtin_amdgcn_mfma_f32_16x16x32_f16(a, b1v, acc1, 0, 0, 0);
            }
            #pragma unroll
            for (int r = 0; r < 4; ++r) {
                int grow = rbase + quad * 4 + r;
                if (grow < N) {
                    float dvr = dinv[grow];
                    gout[(size_t)grow * D + (t0 + 0) * 16 + l16] = __float2half(acc0[r] * dvr);
                    gout[(size_t)grow * D + (t0 + 1) * 16 + l16] = __float2half(acc1[r] * dvr);
                }
            }
            __syncthreads();   // LDS WAR guard before next tile
        }
        grid.sync();
    }

    // ---- P6: final aggregate (dual-row) -> fp32 out ----
    {
        const int gw = gid >> 6;
        const int nw = gsz >> 6;
        const int hf = lane >> 5;
        const int l32 = lane & 31;
        const int npair = (N + 1) / 2;
        for (int p = gw; p < npair; p += nw) {
            int row0 = p * 2;
            int c1 = min(row0 + 1, N - 1);
            float4 a = gather2(ys, rowptr, col, row0, c1, lane);
            int myrow = hf ? c1 : row0;
            int orow = row0 + hf;
            if (orow < N) {
                float dv  = dinv[myrow];
                float4 bb = ((const float4*)b3)[l32];
                float4 r;
                r.x = bb.x + dv * a.x;
                r.y = bb.y + dv * a.y;
                r.z = bb.z + dv * a.z;
                r.w = bb.w + dv * a.w;
                ((float4*)(out + (size_t)orow * D))[l32] = r;
            }
        }
    }
}

// ==================================================================
// Fallback path: R4's 7-dispatch pipeline (used only if cooperative
// launch is rejected by the runtime/capture).
// ==================================================================

__global__ void prep_kernel(const float* __restrict__ W1, const float* __restrict__ W2,
                            const float* __restrict__ W3, __half* __restrict__ WhT,
                            int* __restrict__ cnt, int N) {
    int i = blockIdx.x * blockDim.x + threadIdx.x;
    if (i < 3 * D * D) {
        int l = i >> 14, j = i & 16383, n = j >> 7, k = j & 127;
        const float* W = (l == 0) ? W1 : (l == 1) ? W2 : W3;
        WhT[(size_t)i] = __float2half(W[(size_t)k * D + n]);
    }
    if (i < N) cnt[i] = 0;
}

__global__ void count_rank_kernel(const int* __restrict__ dst, int* __restrict__ cnt,
                                  int* __restrict__ rank, int E) {
    int e0 = (blockIdx.x * blockDim.x + threadIdx.x) * 8;
    if (e0 + 7 < E) {
        int4 da = *(const int4*)(dst + e0);
        int4 db = *(const int4*)(dst + e0 + 4);
        int4 ra, rb;
        ra.x = atomicAdd(&cnt[da.x], 1);
        ra.y = atomicAdd(&cnt[da.y], 1);
        ra.z = atomicAdd(&cnt[da.z], 1);
        ra.w = atomicAdd(&cnt[da.w], 1);
        rb.x = atomicAdd(&cnt[db.x], 1);
        rb.y = atomicAdd(&cnt[db.y], 1);
        rb.z = atomicAdd(&cnt[db.z], 1);
        rb.w = atomicAdd(&cnt[db.w], 1);
        *(int4*)(rank + e0)     = ra;
        *(int4*)(rank + e0 + 4) = rb;
    } else {
        for (int e = e0; e < E; ++e) rank[e] = atomicAdd(&cnt[dst[e]], 1);
    }
}

__global__ __launch_bounds__(1024) void scan_kernel(const int* __restrict__ cnt,
                                                    int* __restrict__ rowptr,
                                                    float* __restrict__ dinv,
                                                    int N) {
    __shared__ int wsum[16];
    int tid  = threadIdx.x;
    int lane = tid & 63;
    int wid  = tid >> 6;
    int C = ((N + 4095) / 4096) * 4;
    int start = tid * C;
    int end   = start + C; if (end > N) end = N;

    int local = 0;
    int i = start;
    for (; i + 3 < end; i += 4) {
        int4 v = *(const int4*)(cnt + i);
        local += v.x + v.y + v.z + v.w;
    }
    for (; i < end; ++i) local += cnt[i];

    int sc = local;
    #pragma unroll
    for (int off = 1; off < 64; off <<= 1) {
        int t = __shfl_up(sc, off, 64);
        if (lane >= off) sc += t;
    }
    if (lane == 63) wsum[wid] = sc;
    __syncthreads();
    if (tid < 16) {
        int w = wsum[tid];
        #pragma unroll
        for (int off = 1; off < 16; off <<= 1) {
            int t = __shfl_up(w, off, 16);
            if (tid >= off) w += t;
        }
        wsum[tid] = w;
    }
    __syncthreads();
    int run = ((wid > 0) ? wsum[wid - 1] : 0) + (sc - local);

    i = start;
    for (; i + 3 < end; i += 4) {
        int4 v = *(const int4*)(cnt + i);
        int4 rp;
        rp.x = run; rp.y = rp.x + v.x; rp.z = rp.y + v.y; rp.w = rp.z + v.z;
        run = rp.w + v.w;
        *(int4*)(rowptr + i) = rp;
        float4 dv;
        dv.x = rsqrtf((float)v.x + 1.0f);
        dv.y = rsqrtf((float)v.y + 1.0f);
        dv.z = rsqrtf((float)v.z + 1.0f);
        dv.w = rsqrtf((float)v.w + 1.0f);
        *(float4*)(dinv + i) = dv;
    }
    for (; i < end; ++i) {
        int v = cnt[i];
        rowptr[i] = run; run += v;
        dinv[i] = rsqrtf((float)v + 1.0f);
    }
    if (tid == 0) rowptr[N] = wsum[15];
}

__global__ __launch_bounds__(256) void fill_gemm1_kernel(
    const int* __restrict__ src, const int* __restrict__ dst,
    const int* __restrict__ rank, const int* __restrict__ rowptr,
    int* __restrict__ col, int E, int fill_blocks,
    const float* __restrict__ X, const __half* __restrict__ WhT,
    const float* __restrict__ dinv, __half* __restrict__ Y, int M) {
    int tid = threadIdx.x;
    if ((int)blockIdx.x < fill_blocks) {
        int e0 = (blockIdx.x * 256 + tid) * 8;
        if (e0 + 7 < E) {
            int4 da = *(const int4*)(dst + e0);
            int4 db = *(const int4*)(dst + e0 + 4);
            int4 ra = *(const int4*)(rank + e0);
            int4 rb = *(const int4*)(rank + e0 + 4);
            int4 sa = *(const int4*)(src + e0);
            int4 sb = *(const int4*)(src + e0 + 4);
            col[rowptr[da.x] + ra.x] = sa.x;
            col[rowptr[da.y] + ra.y] = sa.y;
            col[rowptr[da.z] + ra.z] = sa.z;
            col[rowptr[da.w] + ra.w] = sa.w;
            col[rowptr[db.x] + rb.x] = sb.x;
            col[rowptr[db.y] + rb.y] = sb.y;
            col[rowptr[db.z] + rb.z] = sb.z;
            col[rowptr[db.w] + rb.w] = sb.w;
        } else {
            for (int e = e0; e < E; ++e) col[rowptr[dst[e]] + rank[e]] = src[e];
        }
        return;
    }
    int bid  = blockIdx.x - fill_blocks;
    int wave = tid >> 6;
    int lane = tid & 63;
    int quad = lane >> 4;
    int l16  = lane & 15;
    int m0   = bid * 64 + wave * 16;
    if (m0 >= M) return;

    f32x4 acc[8];
    #pragma unroll
    for (int t = 0; t < 8; ++t) acc[t] = (f32x4)0.0f;
    const float* xrow = X + (size_t)(m0 + l16) * D;
    #pragma unroll
    for (int ks = 0; ks < 4; ++ks) {
        int k0 = ks * 32 + quad * 8;
        float4 x0 = *(const float4*)(xrow + k0);
        float4 x1 = *(const float4*)(xrow + k0 + 4);
        half8 a;
        a[0] = (_Float16)x0.x; a[1] = (_Float16)x0.y;
        a[2] = (_Float16)x0.z; a[3] = (_Float16)x0.w;
        a[4] = (_Float16)x1.x; a[5] = (_Float16)x1.y;
        a[6] = (_Float16)x1.z; a[7] = (_Float16)x1.w;
        #pragma unroll
        for (int t = 0; t < 8; ++t) {
            half8 b = *(const half8*)(WhT + (size_t)(t * 16 + l16) * D + k0);
            acc[t] = __builtin_amdgcn_mfma_f32_16x16x32_f16(a, b, acc[t], 0, 0, 0);
        }
    }
    float4 dv = *(const float4*)(dinv + m0 + quad * 4);
    float dvs[4] = {dv.x, dv.y, dv.z, dv.w};
    #pragma unroll
    for (int t = 0; t < 8; ++t) {
        #pragma unroll
        for (int r = 0; r < 4; ++r) {
            int grow = m0 + quad * 4 + r;
            Y[(size_t)grow * D + t * 16 + l16] = __float2half(acc[t][r] * dvs[r]);
        }
    }
}

__global__ __launch_bounds__(256) void agg_gemm_kernel(
    const __half* __restrict__ ysIn, const int* __restrict__ rowptr,
    const int* __restrict__ col, const float* __restrict__ dinv,
    const float* __restrict__ bias, const __half* __restrict__ WhT,
    __half* __restrict__ ysOut, int M) {
    __shared__ __half lds_h[16 * PADH];
    int tid  = threadIdx.x;
    int wave = tid >> 6;
    int lane = tid & 63;
    int hf   = lane >> 5;
    int l32  = lane & 31;
    int rbase = blockIdx.x * 16;

    float4 bb = ((const float4*)bias)[l32];
    #pragma unroll
    for (int t = 0; t < 2; ++t) {
        int lr0 = wave * 4 + t * 2;
        int row0 = rbase + lr0;
        int c0 = min(row0, M - 1);
        int c1 = min(row0 + 1, M - 1);
        float4 a = gather2(ysIn, rowptr, col, c0, c1, lane);
        int myrow = hf ? c1 : c0;
        float dv = dinv[myrow];
        half4v hv;
        hv[0] = (_Float16)fmaxf(bb.x + dv * a.x, 0.f);
        hv[1] = (_Float16)fmaxf(bb.y + dv * a.y, 0.f);
        hv[2] = (_Float16)fmaxf(bb.z + dv * a.z, 0.f);
        hv[3] = (_Float16)fmaxf(bb.w + dv * a.w, 0.f);
        ((half4v*)(lds_h + (size_t)(lr0 + hf) * PADH))[l32] = hv;
    }
    __syncthreads();

    if (rbase >= M) return;
    int quad = lane >> 4;
    int l16  = lane & 15;
    int t0   = wave * 2;

    f32x4 acc0 = (f32x4)0.0f, acc1 = (f32x4)0.0f;
    const __half* arow = lds_h + (size_t)l16 * PADH;
    #pragma unroll
    for (int ks = 0; ks < 4; ++ks) {
        int k0 = ks * 32 + quad * 8;
        half8 a  = *(const half8*)(arow + k0);
        half8 b0 = *(const half8*)(WhT + (size_t)((t0 + 0) * 16 + l16) * D + k0);
        half8 b1 = *(const half8*)(WhT + (size_t)((t0 + 1) * 16 + l16) * D + k0);
        acc0 = __builtin_amdgcn_mfma_f32_16x16x32_f16(a, b0, acc0, 0, 0, 0);
        acc1 = __builtin_amdgcn_mfma_f32_16x16x32_f16(a, b1, acc1, 0, 0, 0);
    }
    #pragma unroll
    for (int r = 0; r < 4; ++r) {
        int grow = rbase + quad * 4 + r;
        if (grow < M) {
            float dvr = dinv[grow];
            ysOut[(size_t)grow * D + (t0 + 0) * 16 + l16] = __float2half(acc0[r] * dvr);
            ysOut[(size_t)grow * D + (t0 + 1) * 16 + l16] = __float2half(acc1[r] * dvr);
        }
    }
}

__global__ __launch_bounds__(256) void agg_final_kernel(
    const __half* __restrict__ ys, const int* __restrict__ rowptr,
    const int* __restrict__ col, const float* __restrict__ dinv,
    const float* __restrict__ b, float* __restrict__ out, int N) {
    int gwave = (blockIdx.x * blockDim.x + threadIdx.x) >> 6;
    int lane  = threadIdx.x & 63;
    int hf    = lane >> 5;
    int l32   = lane & 31;
    int row0  = gwave * 2;
    if (row0 >= N) return;
    int c1 = min(row0 + 1, N - 1);

    float4 a = gather2(ys, rowptr, col, row0, c1, lane);
    int myrow = hf ? c1 : row0;
    int orow  = row0 + hf;
    if (orow < N) {
        float dv  = dinv[myrow];
        float4 bb = ((const float4*)b)[l32];
        float4 r;
        r.x = bb.x + dv * a.x;
        r.y = bb.y + dv * a.y;
        r.z = bb.z + dv * a.z;
        r.w = bb.w + dv * a.w;
        ((float4*)(out + (size_t)orow * D))[l32] = r;
    }
}

// ---------------- launch ----------------

extern "C" void kernel_launch(void* const* d_in, const int* in_sizes, int n_in,
                              void* d_out, int out_size, void* d_ws, size_t ws_size,
                              hipStream_t stream) {
    const float* x   = (const float*)d_in[0];
    const int*   ei  = (const int*)d_in[1];
    const float* W1  = (const float*)d_in[2];
    const float* b1  = (const float*)d_in[3];
    const float* W2  = (const float*)d_in[4];
    const float* b2  = (const float*)d_in[5];
    const float* W3  = (const float*)d_in[6];
    const float* b3  = (const float*)d_in[7];
    float* out = (float*)d_out;

    int N = in_sizes[0] / D;
    int E = in_sizes[1] / 2;
    const int* src = ei;
    const int* dst = ei + E;

    char* ws = (char*)d_ws;
    size_t off = 0;
    auto alloc = [&](size_t bytes) {
        void* p = ws + off;
        off = (off + bytes + 255) & ~(size_t)255;
        return p;
    };
    __half* ys    = (__half*)alloc((size_t)N * D * sizeof(__half));
    __half* hs    = (__half*)alloc((size_t)N * D * sizeof(__half));
    int*   cnt    = (int*)alloc((size_t)N * sizeof(int));
    int*   rowptr = (int*)alloc((size_t)(N + 1) * sizeof(int));
    float* dinv   = (float*)alloc((size_t)N * sizeof(float));
    int*   rank   = (int*)alloc((size_t)E * sizeof(int));
    int*   col    = (int*)alloc((size_t)E * sizeof(int));
    int*   partials = (int*)alloc((size_t)NB * sizeof(int));
    __half* WhT   = (__half*)alloc((size_t)3 * D * D * sizeof(__half));
    (void)ws_size; (void)n_in; (void)out_size;

    void* args[] = { &x, &src, &dst, &W1, &b1, &W2, &b2, &W3, &b3, &out,
                     &ys, &hs, &cnt, &rowptr, &dinv, &rank, &col, &partials,
                     &WhT, &N, &E };
    hipError_t err = hipLaunchCooperativeKernel((const void*)mega_kernel,
                                                dim3(NB), dim3(NT), args, 0, stream);
    if (err != hipSuccess) {
        // Fallback: R4 multi-dispatch pipeline (identical math).
        int prep_threads = (3 * D * D > N) ? 3 * D * D : N;
        prep_kernel<<<(prep_threads + 255) / 256, 256, 0, stream>>>(W1, W2, W3, WhT, cnt, N);
        const int egrid = ((E + 7) / 8 + 255) / 256;
        count_rank_kernel<<<egrid, 256, 0, stream>>>(dst, cnt, rank, E);
        scan_kernel<<<1, 1024, 0, stream>>>(cnt, rowptr, dinv, N);
        const int gemm1_grid = (N + 63) / 64;
        fill_gemm1_kernel<<<egrid + gemm1_grid, 256, 0, stream>>>(
            src, dst, rank, rowptr, col, E, egrid, x, WhT, dinv, ys, N);
        const int agg_gemm_grid = (N + 15) / 16;
        agg_gemm_kernel<<<agg_gemm_grid, 256, 0, stream>>>(ys, rowptr, col, dinv, b1, WhT + 16384, hs, N);
        agg_gemm_kernel<<<agg_gemm_grid, 256, 0, stream>>>(hs, rowptr, col, dinv, b2, WhT + 32768, ys, N);
        const int aggf_grid = ((N + 1) / 2 * 64 + 255) / 256;
        agg_final_kernel<<<aggf_grid, 256, 0, stream>>>(ys, rowptr, col, dinv, b3, out, N);
    }
}

// Round 8
// 297.977 us; speedup vs baseline: 3.5853x; 3.5853x over previous
//
#include <hip/hip_runtime.h>
#include <hip/hip_fp16.h>
#include <math.h>

#define D 128
#define PADH 136  // LDS row stride in halves (272 B = 17*16: b128-aligned, 2-way bank alias only)

typedef __attribute__((ext_vector_type(8))) _Float16 half8;
typedef __attribute__((ext_vector_type(4))) float f32x4;

// ---------------- prep: WhT[l][n][k] = (half)Wl[k][n]  +  cnt zeroing ----------------

__global__ void prep_kernel(const float* __restrict__ W1, const float* __restrict__ W2,
                            const float* __restrict__ W3, __half* __restrict__ WhT,
                            int* __restrict__ cnt, int N) {
    int i = blockIdx.x * blockDim.x + threadIdx.x;
    if (i < 3 * D * D) {
        int l = i >> 14, j = i & 16383, n = j >> 7, k = j & 127;
        const float* W = (l == 0) ? W1 : (l == 1) ? W2 : W3;
        WhT[(size_t)i] = __float2half(W[(size_t)k * D + n]);
    }
    if (i < N) cnt[i] = 0;
}

// ---------------- graph build ----------------

// rank[e] = arrival order of edge e within its dst bucket; cnt[d] = in-degree
__global__ void count_rank_kernel(const int* __restrict__ dst, int* __restrict__ cnt,
                                  int* __restrict__ rank, int E) {
    int e0 = (blockIdx.x * blockDim.x + threadIdx.x) * 8;
    if (e0 + 7 < E) {
        int4 da = *(const int4*)(dst + e0);
        int4 db = *(const int4*)(dst + e0 + 4);
        int4 ra, rb;
        ra.x = atomicAdd(&cnt[da.x], 1);
        ra.y = atomicAdd(&cnt[da.y], 1);
        ra.z = atomicAdd(&cnt[da.z], 1);
        ra.w = atomicAdd(&cnt[da.w], 1);
        rb.x = atomicAdd(&cnt[db.x], 1);
        rb.y = atomicAdd(&cnt[db.y], 1);
        rb.z = atomicAdd(&cnt[db.z], 1);
        rb.w = atomicAdd(&cnt[db.w], 1);
        *(int4*)(rank + e0)     = ra;
        *(int4*)(rank + e0 + 4) = rb;
    } else {
        for (int e = e0; e < E; ++e) rank[e] = atomicAdd(&cnt[dst[e]], 1);
    }
}

// single-block scan, one barrier pass: per-thread contiguous chunk, two vector sweeps.
__global__ __launch_bounds__(1024) void scan_kernel(const int* __restrict__ cnt,
                                                    int* __restrict__ rowptr,
                                                    float* __restrict__ dinv,
                                                    int N) {
    __shared__ int wsum[16];
    int tid  = threadIdx.x;
    int lane = tid & 63;
    int wid  = tid >> 6;
    int C = ((N + 4095) / 4096) * 4;
    int start = tid * C;
    int end   = start + C; if (end > N) end = N;

    int local = 0;
    int i = start;
    for (; i + 3 < end; i += 4) {
        int4 v = *(const int4*)(cnt + i);
        local += v.x + v.y + v.z + v.w;
    }
    for (; i < end; ++i) local += cnt[i];

    int sc = local;
    #pragma unroll
    for (int off = 1; off < 64; off <<= 1) {
        int t = __shfl_up(sc, off, 64);
        if (lane >= off) sc += t;
    }
    if (lane == 63) wsum[wid] = sc;
    __syncthreads();
    if (tid < 16) {
        int w = wsum[tid];
        #pragma unroll
        for (int off = 1; off < 16; off <<= 1) {
            int t = __shfl_up(w, off, 16);
            if (tid >= off) w += t;
        }
        wsum[tid] = w;
    }
    __syncthreads();
    int run = ((wid > 0) ? wsum[wid - 1] : 0) + (sc - local);

    i = start;
    for (; i + 3 < end; i += 4) {
        int4 v = *(const int4*)(cnt + i);
        int4 rp;
        rp.x = run; rp.y = rp.x + v.x; rp.z = rp.y + v.y; rp.w = rp.z + v.z;
        run = rp.w + v.w;
        *(int4*)(rowptr + i) = rp;
        float4 dv;
        dv.x = rsqrtf((float)v.x + 1.0f);
        dv.y = rsqrtf((float)v.y + 1.0f);
        dv.z = rsqrtf((float)v.z + 1.0f);
        dv.w = rsqrtf((float)v.w + 1.0f);
        *(float4*)(dinv + i) = dv;
    }
    for (; i < end; ++i) {
        int v = cnt[i];
        rowptr[i] = run; run += v;
        dinv[i] = rsqrtf((float)v + 1.0f);
    }
    if (tid == 0) rowptr[N] = wsum[15];
}

// ---------------- quad-row gather ----------------
// Lanes split 4 groups x 16; group g owns one row, lane holds 8 halves (16B).
// One gather instruction fetches FOUR rows' 256B lines; 8-deep unroll keeps
// 32 row-lines in flight per wave (2x R4's dual-row MLP).
// All loop bounds are group-uniform (derived from row only).

__device__ __forceinline__ void gather4(const __half* __restrict__ g,
                                        const int* __restrict__ rowptr,
                                        const int* __restrict__ col,
                                        int row, int lane, float* __restrict__ acc) {
    int grp = lane >> 4;
    int l16 = lane & 15;
    int gb  = grp << 4;
    int s = rowptr[row], e = rowptr[row + 1];

    half8 hs = ((const half8*)(g + (size_t)row * D))[l16];
    float a0 = (float)hs[0], a1 = (float)hs[1], a2 = (float)hs[2], a3 = (float)hs[3];
    float a4 = (float)hs[4], a5 = (float)hs[5], a6 = (float)hs[6], a7 = (float)hs[7];
    float b0 = 0.f, b1 = 0.f, b2 = 0.f, b3 = 0.f, b4 = 0.f, b5 = 0.f, b6 = 0.f, b7 = 0.f;

    for (int base = s; base < e; base += 16) {
        int idx = base + l16;
        int myc = (idx < e) ? col[idx] : 0;
        int nb  = min(16, e - base);
        int j = 0;
        for (; j + 8 <= nb; j += 8) {
            int c0 = __shfl(myc, gb + j + 0), c1 = __shfl(myc, gb + j + 1);
            int c2 = __shfl(myc, gb + j + 2), c3 = __shfl(myc, gb + j + 3);
            int c4 = __shfl(myc, gb + j + 4), c5 = __shfl(myc, gb + j + 5);
            int c6 = __shfl(myc, gb + j + 6), c7 = __shfl(myc, gb + j + 7);
            half8 v0 = ((const half8*)(g + (size_t)c0 * D))[l16];
            half8 v1 = ((const half8*)(g + (size_t)c1 * D))[l16];
            half8 v2 = ((const half8*)(g + (size_t)c2 * D))[l16];
            half8 v3 = ((const half8*)(g + (size_t)c3 * D))[l16];
            half8 v4 = ((const half8*)(g + (size_t)c4 * D))[l16];
            half8 v5 = ((const half8*)(g + (size_t)c5 * D))[l16];
            half8 v6 = ((const half8*)(g + (size_t)c6 * D))[l16];
            half8 v7 = ((const half8*)(g + (size_t)c7 * D))[l16];
            a0 += (float)v0[0]; a1 += (float)v0[1]; a2 += (float)v0[2]; a3 += (float)v0[3];
            a4 += (float)v0[4]; a5 += (float)v0[5]; a6 += (float)v0[6]; a7 += (float)v0[7];
            b0 += (float)v1[0]; b1 += (float)v1[1]; b2 += (float)v1[2]; b3 += (float)v1[3];
            b4 += (float)v1[4]; b5 += (float)v1[5]; b6 += (float)v1[6]; b7 += (float)v1[7];
            a0 += (float)v2[0]; a1 += (float)v2[1]; a2 += (float)v2[2]; a3 += (float)v2[3];
            a4 += (float)v2[4]; a5 += (float)v2[5]; a6 += (float)v2[6]; a7 += (float)v2[7];
            b0 += (float)v3[0]; b1 += (float)v3[1]; b2 += (float)v3[2]; b3 += (float)v3[3];
            b4 += (float)v3[4]; b5 += (float)v3[5]; b6 += (float)v3[6]; b7 += (float)v3[7];
            a0 += (float)v4[0]; a1 += (float)v4[1]; a2 += (float)v4[2]; a3 += (float)v4[3];
            a4 += (float)v4[4]; a5 += (float)v4[5]; a6 += (float)v4[6]; a7 += (float)v4[7];
            b0 += (float)v5[0]; b1 += (float)v5[1]; b2 += (float)v5[2]; b3 += (float)v5[3];
            b4 += (float)v5[4]; b5 += (float)v5[5]; b6 += (float)v5[6]; b7 += (float)v5[7];
            a0 += (float)v6[0]; a1 += (float)v6[1]; a2 += (float)v6[2]; a3 += (float)v6[3];
            a4 += (float)v6[4]; a5 += (float)v6[5]; a6 += (float)v6[6]; a7 += (float)v6[7];
            b0 += (float)v7[0]; b1 += (float)v7[1]; b2 += (float)v7[2]; b3 += (float)v7[3];
            b4 += (float)v7[4]; b5 += (float)v7[5]; b6 += (float)v7[6]; b7 += (float)v7[7];
        }
        for (; j + 4 <= nb; j += 4) {
            int c0 = __shfl(myc, gb + j + 0), c1 = __shfl(myc, gb + j + 1);
            int c2 = __shfl(myc, gb + j + 2), c3 = __shfl(myc, gb + j + 3);
            half8 v0 = ((const half8*)(g + (size_t)c0 * D))[l16];
            half8 v1 = ((const half8*)(g + (size_t)c1 * D))[l16];
            half8 v2 = ((const half8*)(g + (size_t)c2 * D))[l16];
            half8 v3 = ((const half8*)(g + (size_t)c3 * D))[l16];
            a0 += (float)v0[0]; a1 += (float)v0[1]; a2 += (float)v0[2]; a3 += (float)v0[3];
            a4 += (float)v0[4]; a5 += (float)v0[5]; a6 += (float)v0[6]; a7 += (float)v0[7];
            b0 += (float)v1[0]; b1 += (float)v1[1]; b2 += (float)v1[2]; b3 += (float)v1[3];
            b4 += (float)v1[4]; b5 += (float)v1[5]; b6 += (float)v1[6]; b7 += (float)v1[7];
            a0 += (float)v2[0]; a1 += (float)v2[1]; a2 += (float)v2[2]; a3 += (float)v2[3];
            a4 += (float)v2[4]; a5 += (float)v2[5]; a6 += (float)v2[6]; a7 += (float)v2[7];
            b0 += (float)v3[0]; b1 += (float)v3[1]; b2 += (float)v3[2]; b3 += (float)v3[3];
            b4 += (float)v3[4]; b5 += (float)v3[5]; b6 += (float)v3[6]; b7 += (float)v3[7];
        }
        for (; j < nb; ++j) {
            int c = __shfl(myc, gb + j);
            half8 v = ((const half8*)(g + (size_t)c * D))[l16];
            a0 += (float)v[0]; a1 += (float)v[1]; a2 += (float)v[2]; a3 += (float)v[3];
            a4 += (float)v[4]; a5 += (float)v[5]; a6 += (float)v[6]; a7 += (float)v[7];
        }
    }
    acc[0] = a0 + b0; acc[1] = a1 + b1; acc[2] = a2 + b2; acc[3] = a3 + b3;
    acc[4] = a4 + b4; acc[5] = a5 + b5; acc[6] = a6 + b6; acc[7] = a7 + b7;
}

// ---------------- fill + gemm1 (fused by block range) ----------------
// fill: XCD-SHARDED by dst-range: shard = bid&7 rides the round-robin block->XCD
// map so each col line is written from exactly ONE XCD (kills write ping-pong).
// Each shard re-reads the edge arrays sequentially (L3-served).

__global__ __launch_bounds__(256) void fill_gemm1_kernel(
    const int* __restrict__ src, const int* __restrict__ dst,
    const int* __restrict__ rank, const int* __restrict__ rowptr,
    int* __restrict__ col, int E, int fill_blocks, int N,
    const float* __restrict__ X, const __half* __restrict__ WhT,
    const float* __restrict__ dinv, __half* __restrict__ Y, int M) {
    int tid = threadIdx.x;
    if ((int)blockIdx.x < fill_blocks) {
        int shard = blockIdx.x & 7;
        int sub   = blockIdx.x >> 3;
        int nsub  = fill_blocks >> 3;
        int chunk = (N + 7) >> 3;
        int lo = shard * chunk;
        unsigned span = (unsigned)(min(lo + chunk, N) - lo);
        const int NO = (E + 7) / 8;
        for (int c = sub * 256 + tid; c < NO; c += nsub * 256) {
            int e0 = c * 8;
            if (e0 + 7 < E) {
                int4 da = *(const int4*)(dst + e0);
                int4 db = *(const int4*)(dst + e0 + 4);
                bool i0 = (unsigned)(da.x - lo) < span, i1 = (unsigned)(da.y - lo) < span;
                bool i2 = (unsigned)(da.z - lo) < span, i3 = (unsigned)(da.w - lo) < span;
                bool i4 = (unsigned)(db.x - lo) < span, i5 = (unsigned)(db.y - lo) < span;
                bool i6 = (unsigned)(db.z - lo) < span, i7 = (unsigned)(db.w - lo) < span;
                if (i0 | i1 | i2 | i3 | i4 | i5 | i6 | i7) {
                    int4 ra = *(const int4*)(rank + e0);
                    int4 rb = *(const int4*)(rank + e0 + 4);
                    int4 sa = *(const int4*)(src + e0);
                    int4 sb = *(const int4*)(src + e0 + 4);
                    if (i0) col[rowptr[da.x] + ra.x] = sa.x;
                    if (i1) col[rowptr[da.y] + ra.y] = sa.y;
                    if (i2) col[rowptr[da.z] + ra.z] = sa.z;
                    if (i3) col[rowptr[da.w] + ra.w] = sa.w;
                    if (i4) col[rowptr[db.x] + rb.x] = sb.x;
                    if (i5) col[rowptr[db.y] + rb.y] = sb.y;
                    if (i6) col[rowptr[db.z] + rb.z] = sb.z;
                    if (i7) col[rowptr[db.w] + rb.w] = sb.w;
                }
            } else {
                for (int e = e0; e < E; ++e) {
                    int d = dst[e];
                    if ((unsigned)(d - lo) < span) col[rowptr[d] + rank[e]] = src[e];
                }
            }
        }
        return;
    }
    int bid  = blockIdx.x - fill_blocks;
    int wave = tid >> 6;
    int lane = tid & 63;
    int quad = lane >> 4;
    int l16  = lane & 15;
    int m0   = bid * 64 + wave * 16;
    if (m0 >= M) return;

    f32x4 acc[8];
    #pragma unroll
    for (int t = 0; t < 8; ++t) acc[t] = (f32x4)0.0f;
    const float* xrow = X + (size_t)(m0 + l16) * D;
    #pragma unroll
    for (int ks = 0; ks < 4; ++ks) {
        int k0 = ks * 32 + quad * 8;
        float4 x0 = *(const float4*)(xrow + k0);
        float4 x1 = *(const float4*)(xrow + k0 + 4);
        half8 a;
        a[0] = (_Float16)x0.x; a[1] = (_Float16)x0.y;
        a[2] = (_Float16)x0.z; a[3] = (_Float16)x0.w;
        a[4] = (_Float16)x1.x; a[5] = (_Float16)x1.y;
        a[6] = (_Float16)x1.z; a[7] = (_Float16)x1.w;
        #pragma unroll
        for (int t = 0; t < 8; ++t) {
            half8 b = *(const half8*)(WhT + (size_t)(t * 16 + l16) * D + k0);
            acc[t] = __builtin_amdgcn_mfma_f32_16x16x32_f16(a, b, acc[t], 0, 0, 0);
        }
    }
    float4 dv = *(const float4*)(dinv + m0 + quad * 4);
    float dvs[4] = {dv.x, dv.y, dv.z, dv.w};
    #pragma unroll
    for (int t = 0; t < 8; ++t) {
        #pragma unroll
        for (int r = 0; r < 4; ++r) {
            int grow = m0 + quad * 4 + r;
            Y[(size_t)grow * D + t * 16 + l16] = __float2half(acc[t][r] * dvs[r]);
        }
    }
}

// ---------------- fused aggregate + GEMM (layers 2,3) ----------------
// 256 threads / 4 waves / 16 rows; each wave aggregates its 4 rows in ONE
// quad-row gather call, then the GEMM phase (R4 proven) computes 16x128.

__global__ __launch_bounds__(256) void agg_gemm_kernel(
    const __half* __restrict__ ysIn, const int* __restrict__ rowptr,
    const int* __restrict__ col, const float* __restrict__ dinv,
    const float* __restrict__ bias, const __half* __restrict__ WhT,
    __half* __restrict__ ysOut, int M) {
    __shared__ __half lds_h[16 * PADH];
    int tid  = threadIdx.x;
    int wave = tid >> 6;
    int lane = tid & 63;
    int grp  = lane >> 4;
    int l16  = lane & 15;
    int rbase = blockIdx.x * 16;
    int lrow  = wave * 4 + grp;
    int row   = min(rbase + lrow, M - 1);

    float acc8[8];
    gather4(ysIn, rowptr, col, row, lane, acc8);

    float dv = dinv[row];
    float4 bb0 = ((const float4*)bias)[l16 * 2];
    float4 bb1 = ((const float4*)bias)[l16 * 2 + 1];
    half8 hv;
    hv[0] = (_Float16)fmaxf(bb0.x + dv * acc8[0], 0.f);
    hv[1] = (_Float16)fmaxf(bb0.y + dv * acc8[1], 0.f);
    hv[2] = (_Float16)fmaxf(bb0.z + dv * acc8[2], 0.f);
    hv[3] = (_Float16)fmaxf(bb0.w + dv * acc8[3], 0.f);
    hv[4] = (_Float16)fmaxf(bb1.x + dv * acc8[4], 0.f);
    hv[5] = (_Float16)fmaxf(bb1.y + dv * acc8[5], 0.f);
    hv[6] = (_Float16)fmaxf(bb1.z + dv * acc8[6], 0.f);
    hv[7] = (_Float16)fmaxf(bb1.w + dv * acc8[7], 0.f);
    ((half8*)(lds_h + (size_t)lrow * PADH))[l16] = hv;
    __syncthreads();

    int quad = lane >> 4;
    int t0   = wave * 2;
    f32x4 acc0 = (f32x4)0.0f, acc1 = (f32x4)0.0f;
    const __half* arow = lds_h + (size_t)l16 * PADH;
    #pragma unroll
    for (int ks = 0; ks < 4; ++ks) {
        int k0 = ks * 32 + quad * 8;
        half8 a  = *(const half8*)(arow + k0);
        half8 b0 = *(const half8*)(WhT + (size_t)((t0 + 0) * 16 + l16) * D + k0);
        half8 b1 = *(const half8*)(WhT + (size_t)((t0 + 1) * 16 + l16) * D + k0);
        acc0 = __builtin_amdgcn_mfma_f32_16x16x32_f16(a, b0, acc0, 0, 0, 0);
        acc1 = __builtin_amdgcn_mfma_f32_16x16x32_f16(a, b1, acc1, 0, 0, 0);
    }
    #pragma unroll
    for (int r = 0; r < 4; ++r) {
        int grow = rbase + quad * 4 + r;
        if (grow < M) {
            float dvr = dinv[grow];
            ysOut[(size_t)grow * D + (t0 + 0) * 16 + l16] = __float2half(acc0[r] * dvr);
            ysOut[(size_t)grow * D + (t0 + 1) * 16 + l16] = __float2half(acc1[r] * dvr);
        }
    }
}

// ---------------- final aggregate: out = b3 + dinv*(self+neighbors), fp32 ----------------
// quad-row: each wave handles 4 rows via one gather4 call.

__global__ __launch_bounds__(256) void agg_final_kernel(
    const __half* __restrict__ ys, const int* __restrict__ rowptr,
    const int* __restrict__ col, const float* __restrict__ dinv,
    const float* __restrict__ b, float* __restrict__ out, int N) {
    int gwave = (blockIdx.x * blockDim.x + threadIdx.x) >> 6;
    int lane  = threadIdx.x & 63;
    int grp   = lane >> 4;
    int l16   = lane & 15;
    int rbase = gwave * 4;
    if (rbase >= N) return;
    int row = min(rbase + grp, N - 1);

    float acc8[8];
    gather4(ys, rowptr, col, row, lane, acc8);

    if (rbase + grp < N) {
        float dv = dinv[row];
        float4 bb0 = ((const float4*)b)[l16 * 2];
        float4 bb1 = ((const float4*)b)[l16 * 2 + 1];
        float4 r0, r1;
        r0.x = bb0.x + dv * acc8[0];
        r0.y = bb0.y + dv * acc8[1];
        r0.z = bb0.z + dv * acc8[2];
        r0.w = bb0.w + dv * acc8[3];
        r1.x = bb1.x + dv * acc8[4];
        r1.y = bb1.y + dv * acc8[5];
        r1.z = bb1.z + dv * acc8[6];
        r1.w = bb1.w + dv * acc8[7];
        float* op = out + (size_t)row * D + l16 * 8;
        ((float4*)op)[0] = r0;
        ((float4*)op)[1] = r1;
    }
}

// ---------------- launch ----------------

extern "C" void kernel_launch(void* const* d_in, const int* in_sizes, int n_in,
                              void* d_out, int out_size, void* d_ws, size_t ws_size,
                              hipStream_t stream) {
    const float* x   = (const float*)d_in[0];
    const int*   ei  = (const int*)d_in[1];
    const float* W1  = (const float*)d_in[2];
    const float* b1  = (const float*)d_in[3];
    const float* W2  = (const float*)d_in[4];
    const float* b2  = (const float*)d_in[5];
    const float* W3  = (const float*)d_in[6];
    const float* b3  = (const float*)d_in[7];
    float* out = (float*)d_out;

    const int N = in_sizes[0] / D;
    const int E = in_sizes[1] / 2;
    const int* src = ei;
    const int* dst = ei + E;

    char* ws = (char*)d_ws;
    size_t off = 0;
    auto alloc = [&](size_t bytes) {
        void* p = ws + off;
        off = (off + bytes + 255) & ~(size_t)255;
        return p;
    };
    __half* ys    = (__half*)alloc((size_t)N * D * sizeof(__half));
    __half* hs    = (__half*)alloc((size_t)N * D * sizeof(__half));
    int*   cnt    = (int*)alloc((size_t)N * sizeof(int));
    int*   rowptr = (int*)alloc((size_t)(N + 1) * sizeof(int));
    float* dinv   = (float*)alloc((size_t)N * sizeof(float));
    int*   rank   = (int*)alloc((size_t)E * sizeof(int));
    int*   col    = (int*)alloc((size_t)E * sizeof(int));
    __half* WhT   = (__half*)alloc((size_t)3 * D * D * sizeof(__half));
    (void)ws_size; (void)n_in; (void)out_size;

    // 1. prep: W transpose/convert + cnt zero
    int prep_threads = (3 * D * D > N) ? 3 * D * D : N;
    prep_kernel<<<(prep_threads + 255) / 256, 256, 0, stream>>>(W1, W2, W3, WhT, cnt, N);

    // 2-3. count+rank, scan
    const int NO = (E + 7) / 8;
    const int egrid = (NO + 255) / 256;
    count_rank_kernel<<<egrid, 256, 0, stream>>>(dst, cnt, rank, E);
    scan_kernel<<<1, 1024, 0, stream>>>(cnt, rowptr, dinv, N);

    // 4. sharded fill + gemm1 fused (fill blocks: multiple of 8 for XCD sharding)
    const int FB = ((egrid + 7) / 8) * 8;
    const int gemm1_grid = (N + 63) / 64;
    fill_gemm1_kernel<<<FB + gemm1_grid, 256, 0, stream>>>(
        src, dst, rank, rowptr, col, E, FB, N, x, WhT, dinv, ys, N);

    // 5-6. fused aggregate+GEMM with quad-row gather: layer-2 (ys->hs), layer-3 (hs->ys)
    const int agg_gemm_grid = (N + 15) / 16;
    agg_gemm_kernel<<<agg_gemm_grid, 256, 0, stream>>>(ys, rowptr, col, dinv, b1, WhT + 16384, hs, N);
    agg_gemm_kernel<<<agg_gemm_grid, 256, 0, stream>>>(hs, rowptr, col, dinv, b2, WhT + 32768, ys, N);

    // 7. final aggregate (quad-row) -> fp32 out
    const int aggf_grid = (((N + 3) / 4) * 64 + 255) / 256;
    agg_final_kernel<<<aggf_grid, 256, 0, stream>>>(ys, rowptr, col, dinv, b3, out, N);
}